// Round 8
// baseline (421.942 us; speedup 1.0000x reference)
//
#include <hip/hip_runtime.h>
#include <hip/hip_bf16.h>
#include <cstdint>
#include <cstddef>

#define NN 8192
#define FIN 256
#define FOUT 64
#define ALPHA_SLOPE 0.2f
#define EXP_M10 4.5399929762484854e-05f   // exp(-10)

#define JSPLIT 8
#define STRIP 64
#define NSTRIP ((NN / JSPLIT) / STRIP)    // 16
#define RB 128                            // rows per block
#define WPITCH 144                        // bytes per w-row (128 data + 16 pad, residue-4)
#define HPITCH 144                        // bytes per htg-row
#define CP 68                             // slab column pitch (floats)

typedef short s16x8 __attribute__((ext_vector_type(8)));
typedef float f32x4 __attribute__((ext_vector_type(4)));
typedef int   i32x4 __attribute__((ext_vector_type(4)));

__device__ __forceinline__ unsigned short f2bf(float x) {
    union { float f; uint32_t u; } v; v.f = x;
    uint32_t u = v.u;
    return (unsigned short)((u + 0x7FFFu + ((u >> 16) & 1u)) >> 16);  // RNE
}

__device__ __forceinline__ unsigned int pk2(float lo, float hi) {
    return (unsigned int)f2bf(lo) | ((unsigned int)f2bf(hi) << 16);
}

// 4 adj ints + 4 score-inputs -> 2 packed bf16 weights
__device__ __forceinline__ uint2 wpack4(i32x4 a, float4 v, float s1v) {
    float x0 = s1v + v.x, x1 = s1v + v.y, x2 = s1v + v.z, x3 = s1v + v.w;
    float w0 = (a.x > 0) ? __expf(fmaxf(x0, ALPHA_SLOPE * x0)) : EXP_M10;
    float w1 = (a.y > 0) ? __expf(fmaxf(x1, ALPHA_SLOPE * x1)) : EXP_M10;
    float w2 = (a.z > 0) ? __expf(fmaxf(x2, ALPHA_SLOPE * x2)) : EXP_M10;
    float w3 = (a.w > 0) ? __expf(fmaxf(x3, ALPHA_SLOPE * x3)) : EXP_M10;
    uint2 r; r.x = pk2(w0, w1); r.y = pk2(w2, w3);
    return r;
}

// ---------------- Kernel 1: h = input@W, s1 = h@a1, s2 = h@a2, htg = bf16(h)^T ----
__global__ __launch_bounds__(256) void k_h(
    const float* __restrict__ input, const float* __restrict__ W,
    const float* __restrict__ a,
    unsigned short* __restrict__ htg, float* __restrict__ s1, float* __restrict__ s2)
{
    __shared__ __align__(16) unsigned short tile[64][28];
    const int wid  = threadIdx.x >> 6;
    const int lane = threadIdx.x & 63;
    const int i0   = blockIdx.x * 16;
    const int r0   = wid * 4;
    const float* inb = input + (size_t)(i0 + r0) * FIN;

    float acc0 = 0.f, acc1 = 0.f, acc2 = 0.f, acc3 = 0.f;
    #pragma unroll 4
    for (int c = 0; c < FIN; c += 4) {
        float w0 = W[(c + 0) * FOUT + lane];
        float w1 = W[(c + 1) * FOUT + lane];
        float w2 = W[(c + 2) * FOUT + lane];
        float w3 = W[(c + 3) * FOUT + lane];
        float4 x0 = *(const float4*)(inb + 0 * FIN + c);
        float4 x1 = *(const float4*)(inb + 1 * FIN + c);
        float4 x2 = *(const float4*)(inb + 2 * FIN + c);
        float4 x3 = *(const float4*)(inb + 3 * FIN + c);
        acc0 = fmaf(x0.x, w0, fmaf(x0.y, w1, fmaf(x0.z, w2, fmaf(x0.w, w3, acc0))));
        acc1 = fmaf(x1.x, w0, fmaf(x1.y, w1, fmaf(x1.z, w2, fmaf(x1.w, w3, acc1))));
        acc2 = fmaf(x2.x, w0, fmaf(x2.y, w1, fmaf(x2.z, w2, fmaf(x2.w, w3, acc2))));
        acc3 = fmaf(x3.x, w0, fmaf(x3.y, w1, fmaf(x3.z, w2, fmaf(x3.w, w3, acc3))));
    }

    const float a1v = a[lane], a2v = a[FOUT + lane];
    float accs[4] = {acc0, acc1, acc2, acc3};
    #pragma unroll
    for (int r = 0; r < 4; ++r) {
        float v1 = accs[r] * a1v;
        float v2 = accs[r] * a2v;
        #pragma unroll
        for (int off = 32; off; off >>= 1) {
            v1 += __shfl_xor(v1, off);
            v2 += __shfl_xor(v2, off);
        }
        if (lane == 0) { s1[i0 + r0 + r] = v1; s2[i0 + r0 + r] = v2; }
        tile[lane][r0 + r] = f2bf(accs[r]);
    }
    __syncthreads();

    const int feat = threadIdx.x >> 2;
    const int cg   = (threadIdx.x & 3) * 4;
    uint2 q = *(const uint2*)&tile[feat][cg];
    *(uint2*)(htg + (size_t)feat * NN + i0 + cg) = q;
}

// ---------------- Kernel 2: traffic-minimized fused attention (128-row blocks) -----
// Block: 128 rows x 1024-col j-range, 512 threads (8 waves), 2 blocks/CU.
// htg re-read traffic scales as (8192/RB) MB: RB=128 -> 64 MB total (vs 256 @ R7).
// Per 64-col strip (double-buffered, pipelined through VGPRs):
//   stage: w = bf16(exp(masked lrelu)) once per element -> LDS; htg strip -> LDS.
//   mfma : wave = one 16-row group; 2 kk x 5 MFMA (4 feat blocks + denominator).
// Waves own complete rows -> no cross-wave reduction; epilogue writes slab directly.
__global__ __launch_bounds__(512, 4) void k_attn(
    const int* __restrict__ adj,
    const unsigned short* __restrict__ htg,
    const float* __restrict__ s1g, const float* __restrict__ s2g,
    float* __restrict__ slabs)
{
    __shared__ __align__(16) unsigned char wbuf[2][RB * WPITCH];   // 36864 B
    __shared__ __align__(16) unsigned char hbuf[2][64 * HPITCH];   // 18432 B

    const int t    = threadIdx.x;
    const int wid  = t >> 6;
    const int lane = t & 63;
    const int bi   = blockIdx.x >> 3;
    const int js   = blockIdx.x & 7;
    const int i0   = bi * RB;
    const int jbase = js * (NN / JSPLIT);
    const int m    = lane & 15;
    const int quad = lane >> 4;

    // staging coordinates
    const int srow  = t >> 2;            // 0..127 (adj/w row)
    const int scol  = (t & 3) * 16;      // 0..48  (16 ints per thread, contiguous)
    const int sfeat = t >> 3;            // 0..63  (htg row)
    const int scol2 = (t & 7) * 8;       // 0..56  (8 bf16 per thread)
    const float s1v = s1g[i0 + srow];

    const short bd = (m == 0) ? (short)0x3F80 : (short)0;   // bf16 1.0 / 0
    const s16x8 bden = {bd, bd, bd, bd, bd, bd, bd, bd};

    f32x4 acc0 = {0,0,0,0}, acc1 = {0,0,0,0}, acc2 = {0,0,0,0},
          acc3 = {0,0,0,0}, accD = {0,0,0,0};

    const int* adjrow = adj + (size_t)(i0 + srow) * NN + jbase;
    const unsigned short* hrow = htg + (size_t)sfeat * NN + jbase;

    // ---- prologue: stage strip 0 into buffer 0 ----
    {
        i32x4  a0 = *(const i32x4*)(adjrow + scol);
        i32x4  a1 = *(const i32x4*)(adjrow + scol + 4);
        i32x4  a2 = *(const i32x4*)(adjrow + scol + 8);
        i32x4  a3 = *(const i32x4*)(adjrow + scol + 12);
        float4 v0 = *(const float4*)(s2g + jbase + scol);
        float4 v1 = *(const float4*)(s2g + jbase + scol + 4);
        float4 v2 = *(const float4*)(s2g + jbase + scol + 8);
        float4 v3 = *(const float4*)(s2g + jbase + scol + 12);
        s16x8  h0 = *(const s16x8*)(hrow + scol2);

        uint2 pA = wpack4(a0, v0, s1v), pB = wpack4(a1, v1, s1v);
        uint2 pC = wpack4(a2, v2, s1v), pD = wpack4(a3, v3, s1v);
        uint4 q0 = {pA.x, pA.y, pB.x, pB.y};
        uint4 q1 = {pC.x, pC.y, pD.x, pD.y};
        unsigned char* wd = &wbuf[0][srow * WPITCH + (t & 3) * 32];
        *(uint4*)(wd)      = q0;
        *(uint4*)(wd + 16) = q1;
        *(s16x8*)&hbuf[0][sfeat * HPITCH + scol2 * 2] = h0;
    }
    __syncthreads();

    for (int s = 0; s < NSTRIP; ++s) {
        const int cur = s & 1, nxt = cur ^ 1;
        const bool more = (s + 1 < NSTRIP);

        // (a) issue next strip's global loads (waits sink to phase (c))
        i32x4 a0, a1, a2, a3; float4 v0, v1, v2, v3; s16x8 h0;
        if (more) {
            const int jn = (s + 1) * STRIP;
            a0 = *(const i32x4*)(adjrow + jn + scol);
            a1 = *(const i32x4*)(adjrow + jn + scol + 4);
            a2 = *(const i32x4*)(adjrow + jn + scol + 8);
            a3 = *(const i32x4*)(adjrow + jn + scol + 12);
            v0 = *(const float4*)(s2g + jbase + jn + scol);
            v1 = *(const float4*)(s2g + jbase + jn + scol + 4);
            v2 = *(const float4*)(s2g + jbase + jn + scol + 8);
            v3 = *(const float4*)(s2g + jbase + jn + scol + 12);
            h0 = *(const s16x8*)(hrow + jn + scol2);
        }

        // (b) compute current strip from LDS: wave = rows wid*16..wid*16+15
        #pragma unroll
        for (int kk = 0; kk < 2; ++kk) {
            const int cb = kk * 64 + quad * 16;    // byte col offset
            s16x8 af = *(const s16x8*)&wbuf[cur][(wid * 16 + m) * WPITCH + cb];
            s16x8 b0 = *(const s16x8*)&hbuf[cur][(m +  0) * HPITCH + cb];
            s16x8 b1 = *(const s16x8*)&hbuf[cur][(m + 16) * HPITCH + cb];
            s16x8 b2 = *(const s16x8*)&hbuf[cur][(m + 32) * HPITCH + cb];
            s16x8 b3 = *(const s16x8*)&hbuf[cur][(m + 48) * HPITCH + cb];
            acc0 = __builtin_amdgcn_mfma_f32_16x16x32_bf16(af, b0,   acc0, 0, 0, 0);
            acc1 = __builtin_amdgcn_mfma_f32_16x16x32_bf16(af, b1,   acc1, 0, 0, 0);
            acc2 = __builtin_amdgcn_mfma_f32_16x16x32_bf16(af, b2,   acc2, 0, 0, 0);
            acc3 = __builtin_amdgcn_mfma_f32_16x16x32_bf16(af, b3,   acc3, 0, 0, 0);
            accD = __builtin_amdgcn_mfma_f32_16x16x32_bf16(af, bden, accD, 0, 0, 0);
        }

        // (c) finish staging next strip into the other buffer
        if (more) {
            uint2 pA = wpack4(a0, v0, s1v), pB = wpack4(a1, v1, s1v);
            uint2 pC = wpack4(a2, v2, s1v), pD = wpack4(a3, v3, s1v);
            uint4 q0 = {pA.x, pA.y, pB.x, pB.y};
            uint4 q1 = {pC.x, pC.y, pD.x, pD.y};
            unsigned char* wd = &wbuf[nxt][srow * WPITCH + (t & 3) * 32];
            *(uint4*)(wd)      = q0;
            *(uint4*)(wd + 16) = q1;
            *(s16x8*)&hbuf[nxt][sfeat * HPITCH + scol2 * 2] = h0;
        }
        __syncthreads();
    }

    // ---- epilogue: each wave owns complete rows; write slab directly ----
    float* slab = slabs + (size_t)js * ((size_t)NN * CP);
    const int r0 = i0 + wid * 16 + quad * 4;
    #pragma unroll
    for (int reg = 0; reg < 4; ++reg) {
        size_t ro = (size_t)(r0 + reg) * CP;
        slab[ro +  0 + m] = acc0[reg];
        slab[ro + 16 + m] = acc1[reg];
        slab[ro + 32 + m] = acc2[reg];
        slab[ro + 48 + m] = acc3[reg];
        if (m == 0) slab[ro + 64] = accD[reg];
    }
}

// ---------------- Kernel 3: reduce splits, normalize, ELU --------------------------
__global__ __launch_bounds__(256) void k_norm(
    const float* __restrict__ slabs, float* __restrict__ out)
{
    int gid = blockIdx.x * 256 + threadIdx.x;
    int i = gid >> 6, k = gid & 63;
    float num = 0.f, den = 0.f;
    #pragma unroll
    for (int js = 0; js < JSPLIT; ++js) {
        const float* row = slabs + (size_t)js * ((size_t)NN * CP) + (size_t)i * CP;
        num += row[k];
        den += row[64];
    }
    float v = num / den;
    out[gid] = (v > 0.f) ? v : (__expf(v) - 1.f);
}

// ---------------- launch -----------------------------------------------------------
extern "C" void kernel_launch(void* const* d_in, const int* in_sizes, int n_in,
                              void* d_out, int out_size, void* d_ws, size_t ws_size,
                              hipStream_t stream) {
    const float* input = (const float*)d_in[0];
    const int*   adj   = (const int*)d_in[1];
    const float* W     = (const float*)d_in[2];
    const float* a     = (const float*)d_in[3];
    float* out = (float*)d_out;

    char* ws = (char*)d_ws;
    float* slabs = (float*)ws;
    size_t off = (size_t)JSPLIT * NN * CP * sizeof(float);      // 17.8 MB
    unsigned short* htg = (unsigned short*)(ws + off);
    off += (size_t)FOUT * NN * sizeof(unsigned short);          // 1 MB
    float* s1 = (float*)(ws + off); off += NN * sizeof(float);
    float* s2 = (float*)(ws + off);

    k_h   <<<NN / 16, 256, 0, stream>>>(input, W, a, htg, s1, s2);
    k_attn<<<(NN / RB) * JSPLIT, 512, 0, stream>>>(adj, htg, s1, s2, slabs);
    k_norm<<<NN * FOUT / 256, 256, 0, stream>>>(slabs, out);
}

// Round 9
// 413.322 us; speedup vs baseline: 1.0209x; 1.0209x over previous
//
#include <hip/hip_runtime.h>
#include <hip/hip_bf16.h>
#include <cstdint>
#include <cstddef>

#define NN 8192
#define FIN 256
#define FOUT 64
#define ALPHA_SLOPE 0.2f
#define EXP_M10 4.5399929762484854e-05f   // exp(-10)

#define JSPLIT 8
#define STRIP 64
#define NSTRIP ((NN / JSPLIT) / STRIP)    // 16
#define RB 64                             // rows per block
#define WPITCH 144                        // bytes per w-row (128 data + 16 pad, residue-4)
#define HPITCH 144                        // bytes per htg-row
#define CP 68                             // slab column pitch (floats)

typedef short s16x8 __attribute__((ext_vector_type(8)));
typedef float f32x4 __attribute__((ext_vector_type(4)));
typedef int   i32x4 __attribute__((ext_vector_type(4)));

__device__ __forceinline__ unsigned short f2bf(float x) {
    union { float f; uint32_t u; } v; v.f = x;
    uint32_t u = v.u;
    return (unsigned short)((u + 0x7FFFu + ((u >> 16) & 1u)) >> 16);  // RNE
}

// round two floats to bf16 (RNE), accumulate the ROUNDED values into dsum
// (so the scalar denominator matches the bf16 numerator exactly), return packed pair
__device__ __forceinline__ unsigned int rpack2(float a, float b, float& dsum) {
    union { float f; uint32_t u; } va, vb, ra, rb;
    va.f = a; vb.f = b;
    ra.u = (va.u + 0x7FFFu + ((va.u >> 16) & 1u)) & 0xFFFF0000u;
    rb.u = (vb.u + 0x7FFFu + ((vb.u >> 16) & 1u)) & 0xFFFF0000u;
    dsum += ra.f + rb.f;
    return (ra.u >> 16) | rb.u;
}

__device__ __forceinline__ float wval(int a, float s2v, float s1v) {
    float x = s1v + s2v;
    return (a > 0) ? __expf(fmaxf(x, ALPHA_SLOPE * x)) : EXP_M10;
}

// ---------------- Kernel 1: h = input@W, s1 = h@a1, s2 = h@a2, htg = bf16(h)^T ----
__global__ __launch_bounds__(256) void k_h(
    const float* __restrict__ input, const float* __restrict__ W,
    const float* __restrict__ a,
    unsigned short* __restrict__ htg, float* __restrict__ s1, float* __restrict__ s2)
{
    __shared__ __align__(16) unsigned short tile[64][28];
    const int wid  = threadIdx.x >> 6;
    const int lane = threadIdx.x & 63;
    const int i0   = blockIdx.x * 16;
    const int r0   = wid * 4;
    const float* inb = input + (size_t)(i0 + r0) * FIN;

    float acc0 = 0.f, acc1 = 0.f, acc2 = 0.f, acc3 = 0.f;
    #pragma unroll 4
    for (int c = 0; c < FIN; c += 4) {
        float w0 = W[(c + 0) * FOUT + lane];
        float w1 = W[(c + 1) * FOUT + lane];
        float w2 = W[(c + 2) * FOUT + lane];
        float w3 = W[(c + 3) * FOUT + lane];
        float4 x0 = *(const float4*)(inb + 0 * FIN + c);
        float4 x1 = *(const float4*)(inb + 1 * FIN + c);
        float4 x2 = *(const float4*)(inb + 2 * FIN + c);
        float4 x3 = *(const float4*)(inb + 3 * FIN + c);
        acc0 = fmaf(x0.x, w0, fmaf(x0.y, w1, fmaf(x0.z, w2, fmaf(x0.w, w3, acc0))));
        acc1 = fmaf(x1.x, w0, fmaf(x1.y, w1, fmaf(x1.z, w2, fmaf(x1.w, w3, acc1))));
        acc2 = fmaf(x2.x, w0, fmaf(x2.y, w1, fmaf(x2.z, w2, fmaf(x2.w, w3, acc2))));
        acc3 = fmaf(x3.x, w0, fmaf(x3.y, w1, fmaf(x3.z, w2, fmaf(x3.w, w3, acc3))));
    }

    const float a1v = a[lane], a2v = a[FOUT + lane];
    float accs[4] = {acc0, acc1, acc2, acc3};
    #pragma unroll
    for (int r = 0; r < 4; ++r) {
        float v1 = accs[r] * a1v;
        float v2 = accs[r] * a2v;
        #pragma unroll
        for (int off = 32; off; off >>= 1) {
            v1 += __shfl_xor(v1, off);
            v2 += __shfl_xor(v2, off);
        }
        if (lane == 0) { s1[i0 + r0 + r] = v1; s2[i0 + r0 + r] = v2; }
        tile[lane][r0 + r] = f2bf(accs[r]);
    }
    __syncthreads();

    const int feat = threadIdx.x >> 2;
    const int cg   = (threadIdx.x & 3) * 4;
    uint2 q = *(const uint2*)&tile[feat][cg];
    *(uint2*)(htg + (size_t)feat * NN + i0 + cg) = q;
}

// ---------------- Kernel 2: max-occupancy fused attention --------------------------
// Block: 64 rows x 1024-col j-range, 512 threads (8 waves). LDS 36.9 KB ->
// 4 blocks/CU = 32 waves/CU (HW max); __launch_bounds__(512,8) forces VGPR<=64.
// Wave = (rowgroup rg, featgroup fg): owns rows rg*16..+15 x feats fg*32..+31,
// all kk -> only 2 accumulators, zero cross-wave reduction. Denominator computed
// in the STAGING domain as scalar row-sums of the rounded bf16 weights (exactly
// matches the MFMA numerator; saves the 5th MFMA + bden frag).
__global__ __launch_bounds__(512, 8) void k_attn(
    const int* __restrict__ adj,
    const unsigned short* __restrict__ htg,
    const float* __restrict__ s1g, const float* __restrict__ s2g,
    float* __restrict__ slabs)
{
    __shared__ __align__(16) unsigned char wbuf[2][RB * WPITCH];   // 18432 B
    __shared__ __align__(16) unsigned char hbuf[2][64 * HPITCH];   // 18432 B

    const int t    = threadIdx.x;
    const int wid  = t >> 6;
    const int lane = t & 63;
    const int bi   = blockIdx.x >> 3;
    const int js   = blockIdx.x & 7;
    const int i0   = bi * RB;
    const int jbase = js * (NN / JSPLIT);
    const int m    = lane & 15;
    const int quad = lane >> 4;
    const int rg   = wid >> 1;           // row group (0..3)
    const int fg   = wid & 1;            // feature group (0..1)

    // staging coordinates: 64 rows x 64 cols, 8 elems/thread
    const int srow = t >> 3;             // 0..63
    const int scol = (t & 7) * 8;        // 0..56
    const float s1v = s1g[i0 + srow];

    f32x4 acc0 = {0,0,0,0}, acc1 = {0,0,0,0};
    float dsum = 0.f;

    const int* adjrow = adj + (size_t)(i0 + srow) * NN + jbase;
    const unsigned short* hrow = htg + (size_t)srow * NN + jbase;  // srow doubles as feat
    const float* s2p = s2g + jbase;

    // ---- prologue: stage strip 0 into buffer 0 ----
    {
        i32x4  a0 = *(const i32x4*)(adjrow + scol);
        i32x4  a1 = *(const i32x4*)(adjrow + scol + 4);
        float4 v0 = *(const float4*)(s2p + scol);
        float4 v1 = *(const float4*)(s2p + scol + 4);
        s16x8  h0 = *(const s16x8*)(hrow + scol);
        uint4 q;
        q.x = rpack2(wval(a0.x, v0.x, s1v), wval(a0.y, v0.y, s1v), dsum);
        q.y = rpack2(wval(a0.z, v0.z, s1v), wval(a0.w, v0.w, s1v), dsum);
        q.z = rpack2(wval(a1.x, v1.x, s1v), wval(a1.y, v1.y, s1v), dsum);
        q.w = rpack2(wval(a1.z, v1.z, s1v), wval(a1.w, v1.w, s1v), dsum);
        *(uint4*)&wbuf[0][srow * WPITCH + (t & 7) * 16] = q;
        *(s16x8*)&hbuf[0][srow * HPITCH + (t & 7) * 16] = h0;
    }
    __syncthreads();

    for (int s = 0; s < NSTRIP; ++s) {
        const int cur = s & 1, nxt = cur ^ 1;
        const bool more = (s + 1 < NSTRIP);

        // (a) issue next strip's global loads (waits sink to phase (c))
        i32x4 a0, a1; float4 v0, v1; s16x8 h0;
        if (more) {
            const int jn = (s + 1) * STRIP;
            a0 = *(const i32x4*)(adjrow + jn + scol);
            a1 = *(const i32x4*)(adjrow + jn + scol + 4);
            v0 = *(const float4*)(s2p + jn + scol);
            v1 = *(const float4*)(s2p + jn + scol + 4);
            h0 = *(const s16x8*)(hrow + jn + scol);
        }

        // (b) compute current strip: wave (rg, fg), kk = 0..1
        #pragma unroll
        for (int kk = 0; kk < 2; ++kk) {
            const int cb = kk * 64 + quad * 16;
            s16x8 af = *(const s16x8*)&wbuf[cur][(rg * 16 + m) * WPITCH + cb];
            s16x8 b0 = *(const s16x8*)&hbuf[cur][(fg * 32 + m) * HPITCH + cb];
            s16x8 b1 = *(const s16x8*)&hbuf[cur][(fg * 32 + 16 + m) * HPITCH + cb];
            acc0 = __builtin_amdgcn_mfma_f32_16x16x32_bf16(af, b0, acc0, 0, 0, 0);
            acc1 = __builtin_amdgcn_mfma_f32_16x16x32_bf16(af, b1, acc1, 0, 0, 0);
        }

        // (c) finish staging next strip into the other buffer
        if (more) {
            uint4 q;
            q.x = rpack2(wval(a0.x, v0.x, s1v), wval(a0.y, v0.y, s1v), dsum);
            q.y = rpack2(wval(a0.z, v0.z, s1v), wval(a0.w, v0.w, s1v), dsum);
            q.z = rpack2(wval(a1.x, v1.x, s1v), wval(a1.y, v1.y, s1v), dsum);
            q.w = rpack2(wval(a1.z, v1.z, s1v), wval(a1.w, v1.w, s1v), dsum);
            *(uint4*)&wbuf[nxt][srow * WPITCH + (t & 7) * 16] = q;
            *(s16x8*)&hbuf[nxt][srow * HPITCH + (t & 7) * 16] = h0;
        }
        __syncthreads();
    }

    // ---- epilogue ----
    float* slab = slabs + (size_t)js * ((size_t)NN * CP);
    const int r0 = i0 + rg * 16 + quad * 4;
    #pragma unroll
    for (int reg = 0; reg < 4; ++reg) {
        size_t ro = (size_t)(r0 + reg) * CP;
        slab[ro + fg * 32 + m]      = acc0[reg];
        slab[ro + fg * 32 + 16 + m] = acc1[reg];
    }
    // denominator: reduce the 8 staging threads that share srow (same wave)
    dsum += __shfl_xor(dsum, 1);
    dsum += __shfl_xor(dsum, 2);
    dsum += __shfl_xor(dsum, 4);
    if ((t & 7) == 0) slab[(size_t)(i0 + srow) * CP + 64] = dsum;
}

// ---------------- Kernel 3: reduce splits, normalize, ELU --------------------------
__global__ __launch_bounds__(256) void k_norm(
    const float* __restrict__ slabs, float* __restrict__ out)
{
    int gid = blockIdx.x * 256 + threadIdx.x;
    int i = gid >> 6, k = gid & 63;
    float num = 0.f, den = 0.f;
    #pragma unroll
    for (int js = 0; js < JSPLIT; ++js) {
        const float* row = slabs + (size_t)js * ((size_t)NN * CP) + (size_t)i * CP;
        num += row[k];
        den += row[64];
    }
    float v = num / den;
    out[gid] = (v > 0.f) ? v : (__expf(v) - 1.f);
}

// ---------------- launch -----------------------------------------------------------
extern "C" void kernel_launch(void* const* d_in, const int* in_sizes, int n_in,
                              void* d_out, int out_size, void* d_ws, size_t ws_size,
                              hipStream_t stream) {
    const float* input = (const float*)d_in[0];
    const int*   adj   = (const int*)d_in[1];
    const float* W     = (const float*)d_in[2];
    const float* a     = (const float*)d_in[3];
    float* out = (float*)d_out;

    char* ws = (char*)d_ws;
    float* slabs = (float*)ws;
    size_t off = (size_t)JSPLIT * NN * CP * sizeof(float);      // 17.8 MB
    unsigned short* htg = (unsigned short*)(ws + off);
    off += (size_t)FOUT * NN * sizeof(unsigned short);          // 1 MB
    float* s1 = (float*)(ws + off); off += NN * sizeof(float);
    float* s2 = (float*)(ws + off);

    k_h   <<<NN / 16, 256, 0, stream>>>(input, W, a, htg, s1, s2);
    k_attn<<<(NN / RB) * JSPLIT, 512, 0, stream>>>(adj, htg, s1, s2, slabs);
    k_norm<<<NN * FOUT / 256, 256, 0, stream>>>(slabs, out);
}

// Round 10
// 395.912 us; speedup vs baseline: 1.0657x; 1.0440x over previous
//
#include <hip/hip_runtime.h>
#include <hip/hip_bf16.h>
#include <cstdint>
#include <cstddef>

#define NN 8192
#define FIN 256
#define FOUT 64
#define ALPHA_SLOPE 0.2f
#define EXP_M10 4.5399929762484854e-05f   // exp(-10)

#define JSPLIT 4
#define JRANGE (NN / JSPLIT)              // 2048
#define STRIP 128
#define NSTRIP (JRANGE / STRIP)           // 16
#define RB 64                             // rows per block
#define WPITCH 272                        // bytes per w-row (256 data + 16 pad)
#define HPITCH 272                        // bytes per htg-row
#define CP 68                             // slab column pitch (floats)

typedef short s16x8 __attribute__((ext_vector_type(8)));
typedef float f32x4 __attribute__((ext_vector_type(4)));
typedef int   i32x4 __attribute__((ext_vector_type(4)));

__device__ __forceinline__ unsigned short f2bf(float x) {
    union { float f; uint32_t u; } v; v.f = x;
    uint32_t u = v.u;
    return (unsigned short)((u + 0x7FFFu + ((u >> 16) & 1u)) >> 16);  // RNE
}

// round two floats to bf16 (RNE), accumulate the ROUNDED values into dsum
__device__ __forceinline__ unsigned int rpack2(float a, float b, float& dsum) {
    union { float f; uint32_t u; } va, vb, ra, rb;
    va.f = a; vb.f = b;
    ra.u = (va.u + 0x7FFFu + ((va.u >> 16) & 1u)) & 0xFFFF0000u;
    rb.u = (vb.u + 0x7FFFu + ((vb.u >> 16) & 1u)) & 0xFFFF0000u;
    dsum += ra.f + rb.f;
    return (ra.u >> 16) | rb.u;
}

__device__ __forceinline__ float wval(int a, float s2v, float s1v) {
    float x = s1v + s2v;
    return (a > 0) ? __expf(fmaxf(x, ALPHA_SLOPE * x)) : EXP_M10;
}

// ---------------- Kernel 1: h = input@W, s1 = h@a1, s2 = h@a2, htg = bf16(h)^T ----
__global__ __launch_bounds__(256) void k_h(
    const float* __restrict__ input, const float* __restrict__ W,
    const float* __restrict__ a,
    unsigned short* __restrict__ htg, float* __restrict__ s1, float* __restrict__ s2)
{
    __shared__ __align__(16) unsigned short tile[64][28];
    const int wid  = threadIdx.x >> 6;
    const int lane = threadIdx.x & 63;
    const int i0   = blockIdx.x * 16;
    const int r0   = wid * 4;
    const float* inb = input + (size_t)(i0 + r0) * FIN;

    float acc0 = 0.f, acc1 = 0.f, acc2 = 0.f, acc3 = 0.f;
    #pragma unroll 4
    for (int c = 0; c < FIN; c += 4) {
        float w0 = W[(c + 0) * FOUT + lane];
        float w1 = W[(c + 1) * FOUT + lane];
        float w2 = W[(c + 2) * FOUT + lane];
        float w3 = W[(c + 3) * FOUT + lane];
        float4 x0 = *(const float4*)(inb + 0 * FIN + c);
        float4 x1 = *(const float4*)(inb + 1 * FIN + c);
        float4 x2 = *(const float4*)(inb + 2 * FIN + c);
        float4 x3 = *(const float4*)(inb + 3 * FIN + c);
        acc0 = fmaf(x0.x, w0, fmaf(x0.y, w1, fmaf(x0.z, w2, fmaf(x0.w, w3, acc0))));
        acc1 = fmaf(x1.x, w0, fmaf(x1.y, w1, fmaf(x1.z, w2, fmaf(x1.w, w3, acc1))));
        acc2 = fmaf(x2.x, w0, fmaf(x2.y, w1, fmaf(x2.z, w2, fmaf(x2.w, w3, acc2))));
        acc3 = fmaf(x3.x, w0, fmaf(x3.y, w1, fmaf(x3.z, w2, fmaf(x3.w, w3, acc3))));
    }

    const float a1v = a[lane], a2v = a[FOUT + lane];
    float accs[4] = {acc0, acc1, acc2, acc3};
    #pragma unroll
    for (int r = 0; r < 4; ++r) {
        float v1 = accs[r] * a1v;
        float v2 = accs[r] * a2v;
        #pragma unroll
        for (int off = 32; off; off >>= 1) {
            v1 += __shfl_xor(v1, off);
            v2 += __shfl_xor(v2, off);
        }
        if (lane == 0) { s1[i0 + r0 + r] = v1; s2[i0 + r0 + r] = v2; }
        tile[lane][r0 + r] = f2bf(accs[r]);
    }
    __syncthreads();

    const int feat = threadIdx.x >> 2;
    const int cg   = (threadIdx.x & 3) * 4;
    uint2 q = *(const uint2*)&tile[feat][cg];
    *(uint2*)(htg + (size_t)feat * NN + i0 + cg) = q;
}

// ---------------- Kernel 2: fused attention — strip=128, s2 in LDS -----------------
// Block: 64 rows x 2048-col j-range, 512 threads (8 waves), 2 blocks/CU (78 KB LDS).
// s2 for the whole j-range is loaded ONCE into LDS (kills the per-thread-redundant
// global s2 loads = ~adj-sized hidden L1-port traffic in R2..R9). Per 128-col strip
// (R7's proven cadence): prefetch next adj/htg into VGPRs, compute current (4 kk x
// 2 MFMA per wave), stage next (wvals from s2-LDS + rpack). Wave = (rowgroup,
// featgroup): complete rows, scalar dsum denominator, no cross-wave reduction.
__global__ __launch_bounds__(512, 4) void k_attn(
    const int* __restrict__ adj,
    const unsigned short* __restrict__ htg,
    const float* __restrict__ s1g, const float* __restrict__ s2g,
    float* __restrict__ slabs)
{
    __shared__ __align__(16) unsigned char wbuf[2][RB * WPITCH];   // 34816 B
    __shared__ __align__(16) unsigned char hbuf[2][64 * HPITCH];   // 34816 B
    __shared__ __align__(16) float s2buf[JRANGE];                  // 8192 B

    const int t    = threadIdx.x;
    const int wid  = t >> 6;
    const int lane = t & 63;
    const int bi   = blockIdx.x >> 2;
    const int js   = blockIdx.x & 3;
    const int i0   = bi * RB;
    const int jbase = js * JRANGE;
    const int m    = lane & 15;
    const int quad = lane >> 4;
    const int rg   = wid >> 1;           // row group (0..3)
    const int fg   = wid & 1;            // feature group (0..1)

    // staging coordinates: 64 rows x 128 cols, 16 elems/thread
    const int srow = t >> 3;             // 0..63 (adj row; doubles as htg feat)
    const int scol = (t & 7) * 16;       // 0..112
    const float s1v = s1g[i0 + srow];

    f32x4 acc0 = {0,0,0,0}, acc1 = {0,0,0,0};
    float dsum = 0.f;

    const int* adjrow = adj + (size_t)(i0 + srow) * NN + jbase + scol;
    const unsigned short* hrow = htg + (size_t)srow * NN + jbase + scol;

    // ---- prologue: fill s2buf; stage strip 0 (using global s2 this once) ----
    {
        *(float4*)&s2buf[t * 4] = *(const float4*)(s2g + jbase + t * 4);

        i32x4  a0 = *(const i32x4*)(adjrow);
        i32x4  a1 = *(const i32x4*)(adjrow + 4);
        i32x4  a2 = *(const i32x4*)(adjrow + 8);
        i32x4  a3 = *(const i32x4*)(adjrow + 12);
        float4 v0 = *(const float4*)(s2g + jbase + scol);
        float4 v1 = *(const float4*)(s2g + jbase + scol + 4);
        float4 v2 = *(const float4*)(s2g + jbase + scol + 8);
        float4 v3 = *(const float4*)(s2g + jbase + scol + 12);
        s16x8  h0 = *(const s16x8*)(hrow);
        s16x8  h1 = *(const s16x8*)(hrow + 8);

        uint4 q0, q1;
        q0.x = rpack2(wval(a0.x, v0.x, s1v), wval(a0.y, v0.y, s1v), dsum);
        q0.y = rpack2(wval(a0.z, v0.z, s1v), wval(a0.w, v0.w, s1v), dsum);
        q0.z = rpack2(wval(a1.x, v1.x, s1v), wval(a1.y, v1.y, s1v), dsum);
        q0.w = rpack2(wval(a1.z, v1.z, s1v), wval(a1.w, v1.w, s1v), dsum);
        q1.x = rpack2(wval(a2.x, v2.x, s1v), wval(a2.y, v2.y, s1v), dsum);
        q1.y = rpack2(wval(a2.z, v2.z, s1v), wval(a2.w, v2.w, s1v), dsum);
        q1.z = rpack2(wval(a3.x, v3.x, s1v), wval(a3.y, v3.y, s1v), dsum);
        q1.w = rpack2(wval(a3.z, v3.z, s1v), wval(a3.w, v3.w, s1v), dsum);
        unsigned char* wd = &wbuf[0][srow * WPITCH + scol * 2];
        *(uint4*)(wd)      = q0;
        *(uint4*)(wd + 16) = q1;
        unsigned char* hd = &hbuf[0][srow * HPITCH + scol * 2];
        *(s16x8*)(hd)      = h0;
        *(s16x8*)(hd + 16) = h1;
    }
    __syncthreads();

    for (int s = 0; s < NSTRIP; ++s) {
        const int cur = s & 1, nxt = cur ^ 1;
        const bool more = (s + 1 < NSTRIP);

        // (a) issue next strip's global loads (waits sink to phase (c))
        i32x4 a0, a1, a2, a3; s16x8 h0, h1;
        if (more) {
            const int jn = (s + 1) * STRIP;
            a0 = *(const i32x4*)(adjrow + jn);
            a1 = *(const i32x4*)(adjrow + jn + 4);
            a2 = *(const i32x4*)(adjrow + jn + 8);
            a3 = *(const i32x4*)(adjrow + jn + 12);
            h0 = *(const s16x8*)(hrow + jn);
            h1 = *(const s16x8*)(hrow + jn + 8);
        }

        // (b) compute current strip: wave (rg, fg), kk = 0..3
        #pragma unroll
        for (int kk = 0; kk < 4; ++kk) {
            const int cb = kk * 64 + quad * 16;
            s16x8 af = *(const s16x8*)&wbuf[cur][(rg * 16 + m) * WPITCH + cb];
            s16x8 b0 = *(const s16x8*)&hbuf[cur][(fg * 32 + m) * HPITCH + cb];
            s16x8 b1 = *(const s16x8*)&hbuf[cur][(fg * 32 + 16 + m) * HPITCH + cb];
            acc0 = __builtin_amdgcn_mfma_f32_16x16x32_bf16(af, b0, acc0, 0, 0, 0);
            acc1 = __builtin_amdgcn_mfma_f32_16x16x32_bf16(af, b1, acc1, 0, 0, 0);
        }

        // (c) stage next strip (s2 from LDS, adj/htg from (a) prefetch)
        if (more) {
            const int jn = (s + 1) * STRIP;
            float4 v0 = *(const float4*)&s2buf[jn + scol];
            float4 v1 = *(const float4*)&s2buf[jn + scol + 4];
            float4 v2 = *(const float4*)&s2buf[jn + scol + 8];
            float4 v3 = *(const float4*)&s2buf[jn + scol + 12];
            uint4 q0, q1;
            q0.x = rpack2(wval(a0.x, v0.x, s1v), wval(a0.y, v0.y, s1v), dsum);
            q0.y = rpack2(wval(a0.z, v0.z, s1v), wval(a0.w, v0.w, s1v), dsum);
            q0.z = rpack2(wval(a1.x, v1.x, s1v), wval(a1.y, v1.y, s1v), dsum);
            q0.w = rpack2(wval(a1.z, v1.z, s1v), wval(a1.w, v1.w, s1v), dsum);
            q1.x = rpack2(wval(a2.x, v2.x, s1v), wval(a2.y, v2.y, s1v), dsum);
            q1.y = rpack2(wval(a2.z, v2.z, s1v), wval(a2.w, v2.w, s1v), dsum);
            q1.z = rpack2(wval(a3.x, v3.x, s1v), wval(a3.y, v3.y, s1v), dsum);
            q1.w = rpack2(wval(a3.z, v3.z, s1v), wval(a3.w, v3.w, s1v), dsum);
            unsigned char* wd = &wbuf[nxt][srow * WPITCH + scol * 2];
            *(uint4*)(wd)      = q0;
            *(uint4*)(wd + 16) = q1;
            unsigned char* hd = &hbuf[nxt][srow * HPITCH + scol * 2];
            *(s16x8*)(hd)      = h0;
            *(s16x8*)(hd + 16) = h1;
        }
        __syncthreads();
    }

    // ---- epilogue: direct slab writes (waves own complete rows) ----
    float* slab = slabs + (size_t)js * ((size_t)NN * CP);
    const int r0 = i0 + rg * 16 + quad * 4;
    #pragma unroll
    for (int reg = 0; reg < 4; ++reg) {
        size_t ro = (size_t)(r0 + reg) * CP;
        slab[ro + fg * 32 + m]      = acc0[reg];
        slab[ro + fg * 32 + 16 + m] = acc1[reg];
    }
    // denominator: reduce the 8 staging threads sharing srow (same wave)
    dsum += __shfl_xor(dsum, 1);
    dsum += __shfl_xor(dsum, 2);
    dsum += __shfl_xor(dsum, 4);
    if ((t & 7) == 0) slab[(size_t)(i0 + srow) * CP + 64] = dsum;
}

// ---------------- Kernel 3: reduce splits, normalize, ELU --------------------------
__global__ __launch_bounds__(256) void k_norm(
    const float* __restrict__ slabs, float* __restrict__ out)
{
    int gid = blockIdx.x * 256 + threadIdx.x;
    int i = gid >> 6, k = gid & 63;
    float num = 0.f, den = 0.f;
    #pragma unroll
    for (int js = 0; js < JSPLIT; ++js) {
        const float* row = slabs + (size_t)js * ((size_t)NN * CP) + (size_t)i * CP;
        num += row[k];
        den += row[64];
    }
    float v = num / den;
    out[gid] = (v > 0.f) ? v : (__expf(v) - 1.f);
}

// ---------------- launch -----------------------------------------------------------
extern "C" void kernel_launch(void* const* d_in, const int* in_sizes, int n_in,
                              void* d_out, int out_size, void* d_ws, size_t ws_size,
                              hipStream_t stream) {
    const float* input = (const float*)d_in[0];
    const int*   adj   = (const int*)d_in[1];
    const float* W     = (const float*)d_in[2];
    const float* a     = (const float*)d_in[3];
    float* out = (float*)d_out;

    char* ws = (char*)d_ws;
    float* slabs = (float*)ws;
    size_t off = (size_t)JSPLIT * NN * CP * sizeof(float);      // 8.9 MB
    unsigned short* htg = (unsigned short*)(ws + off);
    off += (size_t)FOUT * NN * sizeof(unsigned short);          // 1 MB
    float* s1 = (float*)(ws + off); off += NN * sizeof(float);
    float* s2 = (float*)(ws + off);

    k_h   <<<NN / 16, 256, 0, stream>>>(input, W, a, htg, s1, s2);
    k_attn<<<(NN / RB) * JSPLIT, 512, 0, stream>>>(adj, htg, s1, s2, slabs);
    k_norm<<<NN * FOUT / 256, 256, 0, stream>>>(slabs, out);
}